// Round 5
// baseline (168.365 us; speedup 1.0000x reference)
//
#include <hip/hip_runtime.h>

// EuclideanLoss: loss = (1/(B*N)) * sum_{b,n} w_n * sqrt(sum_d (x[b,n,d]-y[b,d,n])^2)
// w_n = 1.5 for n in {1,2}. B=32, N=8192, D=64, fp32. 128 MiB moved -> ~21 us floor.
//
// R4: R0-R3 all defeated by the compiler's register-pressure-first scheduler
// (VGPR pinned at 20-40, loads batched ~2-4 deep -> ~3 TB/s effective).
// Make MLP structural: __builtin_amdgcn_global_load_lds (async, zero data
// VGPRs, vmcnt-tracked). Each wave issues 20 back-to-back async copies
// (4x 1KB x-chunks + 16x 256B y-rows) = 8 KB in flight per wave, guaranteed.
// 32 KB LDS/block -> 5 blocks/CU resident -> up to 160 KB outstanding per CU.
// All global accesses dense (x tile contiguous 16 KB; y rows 256 B).
// Compute reads LDS with diagonal swizzle (x 4-way, y 2-way conflicts - cheap).

constexpr int B  = 32;
constexpr int N  = 8192;
constexpr int D  = 64;
constexpr int TN = 64;     // n per tile (block)

#define GLD_LDS(gp, lp, sz)                                                              \
    __builtin_amdgcn_global_load_lds(                                                    \
        (const __attribute__((address_space(1))) void*)(gp),                             \
        (__attribute__((address_space(3))) void*)(lp), (sz), 0, 0)

__global__ __launch_bounds__(256) void euclid_loss_kernel(
    const float* __restrict__ x,   // [B, N, D]
    const float* __restrict__ y,   // [B, D, N]
    float* __restrict__ out)       // [1]
{
    // No padding allowed: global_load_lds writes base + lane*size contiguously.
    __shared__ float x_s[TN * D];  // [n][d], row stride 64
    __shared__ float y_s[D * TN];  // [d][n], row stride 64

    const int tid  = threadIdx.x;
    const int wave = tid >> 6;
    const int lane = tid & 63;
    const int n0   = blockIdx.x * TN;
    const int b    = blockIdx.y;

    const float* xg = x + ((size_t)b * N + n0) * D;   // contiguous 16 KB tile
    const float* yg = y + (size_t)b * D * N + n0;     // 64 rows of 256 B, stride N

    // x: 16 chunks of 1 KB; wave w issues chunks 4w..4w+3. Per-lane gaddr =
    // chunk + lane*16 B; LDS dst = uniform chunk base (HW adds lane*16).
#pragma unroll
    for (int j = 0; j < 4; ++j) {
        const int c = wave * 4 + j;
        GLD_LDS(xg + c * 256 + lane * 4, x_s + c * 256, 16);
    }
    // y: 64 rows of 256 B; wave w issues rows 16w..16w+15. Per-lane gaddr =
    // row + lane*4 B; LDS dst = uniform row base (HW adds lane*4).
#pragma unroll
    for (int j = 0; j < 16; ++j) {
        const int d = wave * 16 + j;
        GLD_LDS(yg + (size_t)d * N + lane, y_s + d * TN, 4);
    }

    __syncthreads();   // emits s_waitcnt vmcnt(0) + s_barrier: staging complete

    // Thread (wave=q, lane=n) accumulates d-quarter q for local n, diagonal
    // order so x-reads spread over 16 banks (4-way) and y-reads are 2-way.
    float acc = 0.0f;
#pragma unroll
    for (int s = 0; s < 16; ++s) {
        const int d  = wave * 16 + ((lane + s) & 15);
        const float df = x_s[lane * D + d] - y_s[d * TN + lane];
        acc += df * df;
    }

    __syncthreads();               // all LDS reads done before reuse
    x_s[wave * TN + lane] = acc;   // part[quarter][n]
    __syncthreads();

    if (tid < TN) {
        const float s = x_s[tid] + x_s[TN + tid] + x_s[2 * TN + tid] + x_s[3 * TN + tid];
        const int   n = n0 + tid;
        const float w = (n == 1 || n == 2) ? 1.5f : 1.0f;
        float v = w * __builtin_sqrtf(s);
#pragma unroll
        for (int off = 32; off > 0; off >>= 1) v += __shfl_down(v, off, 64);
        if (tid == 0)
            atomicAdd(out, v * (1.0f / (float)(B * N)));
    }
}

extern "C" void kernel_launch(void* const* d_in, const int* in_sizes, int n_in,
                              void* d_out, int out_size, void* d_ws, size_t ws_size,
                              hipStream_t stream) {
    const float* x = (const float*)d_in[0];
    const float* y = (const float*)d_in[1];
    float* out = (float*)d_out;

    // d_out is re-poisoned to 0xAA before every timed launch; zero it first.
    hipMemsetAsync(out, 0, sizeof(float), stream);

    dim3 grid(N / TN, B);          // (128, 32) = 4096 blocks
    euclid_loss_kernel<<<grid, 256, 0, stream>>>(x, y, out);
}

// Round 6
// 141.865 us; speedup vs baseline: 1.1868x; 1.1868x over previous
//
#include <hip/hip_runtime.h>

// EuclideanLoss: loss = (1/(B*N)) * sum_{b,n} w_n * sqrt(sum_d (x[b,n,d]-y[b,d,n])^2)
// w_n = 1.5 for n in {1,2}. B=32, N=8192, D=64, fp32. 128 MiB moved.
//
// R5: evidence from R3/R4 — kernel time identical whether data comes from HBM
// (FETCH 65 MB) or L3 (FETCH 131 KB), and duration tracks BLOCK COUNT across
// wildly different kernels (4096 blocks -> 62-65 us; 2048 -> 45; 1024 -> 49).
// Theory: the same-address atomicAdd stream serializes (~15 ns each) and its
// drain gates kernel completion (empty CUs -> 23% occupancy). Minimal-diff
// test: R4 staging unchanged, atomic replaced by per-block partial store to
// d_ws + a tiny 1-block reduce kernel.

constexpr int B  = 32;
constexpr int N  = 8192;
constexpr int D  = 64;
constexpr int TN = 64;     // n per tile (block)
constexpr int NBLK = (N / TN) * B;   // 4096 partials

#define GLD_LDS(gp, lp, sz)                                                              \
    __builtin_amdgcn_global_load_lds(                                                    \
        (const __attribute__((address_space(1))) void*)(gp),                             \
        (__attribute__((address_space(3))) void*)(lp), (sz), 0, 0)

__global__ __launch_bounds__(256) void euclid_loss_kernel(
    const float* __restrict__ x,   // [B, N, D]
    const float* __restrict__ y,   // [B, D, N]
    float* __restrict__ ws)        // [NBLK] per-block partials
{
    // No padding allowed: global_load_lds writes base + lane*size contiguously.
    __shared__ float x_s[TN * D];  // [n][d], row stride 64
    __shared__ float y_s[D * TN];  // [d][n], row stride 64

    const int tid  = threadIdx.x;
    const int wave = tid >> 6;
    const int lane = tid & 63;
    const int n0   = blockIdx.x * TN;
    const int b    = blockIdx.y;

    const float* xg = x + ((size_t)b * N + n0) * D;   // contiguous 16 KB tile
    const float* yg = y + (size_t)b * D * N + n0;     // 64 rows of 256 B, stride N

    // x: 16 chunks of 1 KB; wave w issues chunks 4w..4w+3.
#pragma unroll
    for (int j = 0; j < 4; ++j) {
        const int c = wave * 4 + j;
        GLD_LDS(xg + c * 256 + lane * 4, x_s + c * 256, 16);
    }
    // y: 64 rows of 256 B; wave w issues rows 16w..16w+15.
#pragma unroll
    for (int j = 0; j < 16; ++j) {
        const int d = wave * 16 + j;
        GLD_LDS(yg + (size_t)d * N + lane, y_s + d * TN, 4);
    }

    __syncthreads();   // vmcnt(0) drain + barrier: staging complete

    // Thread (wave=q, lane=n) accumulates d-quarter q for local n, diagonal
    // order so x-reads spread over 16 banks (4-way) and y-reads are 2-way.
    float acc = 0.0f;
#pragma unroll
    for (int s = 0; s < 16; ++s) {
        const int d  = wave * 16 + ((lane + s) & 15);
        const float df = x_s[lane * D + d] - y_s[d * TN + lane];
        acc += df * df;
    }

    __syncthreads();               // all LDS reads done before reuse
    x_s[wave * TN + lane] = acc;   // part[quarter][n]
    __syncthreads();

    if (tid < TN) {
        const float s = x_s[tid] + x_s[TN + tid] + x_s[2 * TN + tid] + x_s[3 * TN + tid];
        const int   n = n0 + tid;
        const float w = (n == 1 || n == 2) ? 1.5f : 1.0f;
        float v = w * __builtin_sqrtf(s);
#pragma unroll
        for (int off = 32; off > 0; off >>= 1) v += __shfl_down(v, off, 64);
        if (tid == 0)
            ws[blockIdx.y * gridDim.x + blockIdx.x] = v;   // plain store, no atomic
    }
}

__global__ __launch_bounds__(256) void reduce_kernel(
    const float* __restrict__ ws,  // [NBLK]
    float* __restrict__ out)       // [1]
{
    const int tid = threadIdx.x;
    float v = 0.0f;
#pragma unroll
    for (int j = 0; j < NBLK / (256 * 4); ++j) {   // 4 float4 per thread
        const float4 p = *reinterpret_cast<const float4*>(ws + j * 1024 + tid * 4);
        v += p.x + p.y + p.z + p.w;
    }
#pragma unroll
    for (int off = 32; off > 0; off >>= 1) v += __shfl_down(v, off, 64);

    __shared__ float wsum[4];
    if ((tid & 63) == 0) wsum[tid >> 6] = v;
    __syncthreads();
    if (tid == 0)
        out[0] = (wsum[0] + wsum[1] + wsum[2] + wsum[3]) * (1.0f / (float)(B * N));
}

extern "C" void kernel_launch(void* const* d_in, const int* in_sizes, int n_in,
                              void* d_out, int out_size, void* d_ws, size_t ws_size,
                              hipStream_t stream) {
    const float* x = (const float*)d_in[0];
    const float* y = (const float*)d_in[1];
    float* out = (float*)d_out;
    float* ws  = (float*)d_ws;

    dim3 grid(N / TN, B);          // (128, 32) = 4096 blocks
    euclid_loss_kernel<<<grid, 256, 0, stream>>>(x, y, ws);
    reduce_kernel<<<1, 256, 0, stream>>>(ws, out);
}